// Round 4
// baseline (98.072 us; speedup 1.0000x reference)
//
#include <hip/hip_runtime.h>

// x: (2048, 200, 11, 11) f32.  N = 2048*200*121 = 49,561,600 (divisible by 4).
// out[b,c,i,j] = exp( -(x[b,c,i,j]-x[b,c,5,5])^2 / S  -  (|i-5|+|j-5|)/2 )
// where S = sum over ALL elements of (x - per-plane-center)^2.
//
// R4 experiment: out-store via inline asm "nt sc0 sc1" to bypass the
// Infinity Cache so x stays L3-resident for K2's re-read.
// Traffic model: all-HBM = 594 MB (~97 us observed); with L3 retention
// of x the steady state is ~198 MB HBM write + L3 reads (~65-75 us).

#define N_TOTAL    49561600
#define N4         (N_TOTAL / 4)     // 12,390,400
#define PLANE      121
#define CENTER_OFF 60                // 5*11 + 5
#define NBLOCKS    2048
#define NTHREADS   256

typedef float f32x4 __attribute__((ext_vector_type(4)));

__global__ __launch_bounds__(NTHREADS) void fuzzy_reduce_kernel(
    const float* __restrict__ x, float* __restrict__ partials)
{
    float acc = 0.0f;
    for (int i4 = blockIdx.x * NTHREADS + threadIdx.x; i4 < N4;
         i4 += NBLOCKS * NTHREADS) {
        f32x4 v = reinterpret_cast<const f32x4*>(x)[i4];
        const int base = i4 * 4;
        // quad spans at most 2 planes: 2 divides + 2 center loads (was 4+4)
        const int p0   = base / PLANE;            // magic-mul
        const int p3   = (base + 3) / PLANE;      // magic-mul
        const int bnd  = (p0 + 1) * PLANE;        // first idx of next plane
        const float cv0 = x[p0 * PLANE + CENTER_OFF];
        const float cv3 = x[p3 * PLANE + CENTER_OFF];
        #pragma unroll
        for (int j = 0; j < 4; ++j) {
            float cv = (base + j >= bnd) ? cv3 : cv0;
            float d  = v[j] - cv;
            acc = fmaf(d, d, acc);
        }
    }
    // 64-lane shuffle reduce, then cross-wave via LDS
    #pragma unroll
    for (int off = 32; off > 0; off >>= 1)
        acc += __shfl_down(acc, off, 64);
    __shared__ float wsum[NTHREADS / 64];
    const int lane = threadIdx.x & 63;
    const int wid  = threadIdx.x >> 6;
    if (lane == 0) wsum[wid] = acc;
    __syncthreads();
    if (threadIdx.x == 0)
        partials[blockIdx.x] = wsum[0] + wsum[1] + wsum[2] + wsum[3];
}

__global__ __launch_bounds__(NTHREADS) void fuzzy_finalize_kernel(
    const float* __restrict__ x, const float* __restrict__ partials,
    float* __restrict__ out)
{
    // --- re-reduce the 2048 partials in every block (~8 loads/thread) ---
    float s = 0.0f;
    for (int i = threadIdx.x; i < NBLOCKS; i += NTHREADS)
        s += partials[i];
    #pragma unroll
    for (int off = 32; off > 0; off >>= 1)
        s += __shfl_down(s, off, 64);

    __shared__ float wsum[NTHREADS / 64];
    __shared__ float dist_half[PLANE];
    const int lane = threadIdx.x & 63;
    const int wid  = threadIdx.x >> 6;
    if (lane == 0) wsum[wid] = s;
    if (threadIdx.x < PLANE) {
        int i = threadIdx.x / 11;
        int j = threadIdx.x % 11;
        dist_half[threadIdx.x] =
            0.5f * (fabsf((float)(i - 5)) + fabsf((float)(j - 5)));
    }
    __syncthreads();
    const float inv_total = 1.0f / (wsum[0] + wsum[1] + wsum[2] + wsum[3]);

    // --- main stream: x (hopefully L3-resident) -> out (bypass store) ---
    for (int i4 = blockIdx.x * NTHREADS + threadIdx.x; i4 < N4;
         i4 += NBLOCKS * NTHREADS) {
        f32x4 v = reinterpret_cast<const f32x4*>(x)[i4];
        f32x4 r;
        const int base = i4 * 4;
        const int p0   = base / PLANE;
        const int p3   = (base + 3) / PLANE;
        const int bnd  = (p0 + 1) * PLANE;
        const float cv0 = x[p0 * PLANE + CENTER_OFF];
        const float cv3 = x[p3 * PLANE + CENTER_OFF];
        #pragma unroll
        for (int j = 0; j < 4; ++j) {
            int idx    = base + j;
            int within = idx - ((idx >= bnd) ? bnd : (p0 * PLANE));
            // 'within' for elements in plane p0: idx - p0*PLANE;
            // for elements past bnd (plane p0+1): idx - bnd. Correct since
            // bnd = (p0+1)*PLANE.
            float cv = (idx >= bnd) ? cv3 : cv0;
            float d  = v[j] - cv;
            r[j] = __expf(fmaf(-(d * d), inv_total, -dist_half[within]));
        }
        f32x4* dst = reinterpret_cast<f32x4*>(out) + i4;
        // nt + sc0 + sc1: non-temporal, system-scope -> strongest
        // cache-bypass hint available on gfx950 MUBUF/FLAT stores.
        asm volatile("global_store_dwordx4 %0, %1, off nt sc0 sc1"
                     :: "v"(dst), "v"(r) : "memory");
    }
}

extern "C" void kernel_launch(void* const* d_in, const int* in_sizes, int n_in,
                              void* d_out, int out_size, void* d_ws, size_t ws_size,
                              hipStream_t stream)
{
    const float* x        = (const float*)d_in[0];
    float*       out      = (float*)d_out;
    float*       partials = (float*)d_ws;   // 2048 floats, fully rewritten each call

    fuzzy_reduce_kernel<<<NBLOCKS, NTHREADS, 0, stream>>>(x, partials);
    fuzzy_finalize_kernel<<<NBLOCKS, NTHREADS, 0, stream>>>(x, partials, out);
}